// Round 1
// baseline (101.801 us; speedup 1.0000x reference)
//
#include <hip/hip_runtime.h>
#include <math.h>

#define WAVES_PER_BLOCK 4

typedef float v2f __attribute__((ext_vector_type(2)));
typedef float v4f __attribute__((ext_vector_type(4)));

__device__ __forceinline__ v2f v2_fma(v2f a, v2f b, v2f c) {
    return __builtin_elementwise_fma(a, b, c);
}
__device__ __forceinline__ v2f v2_max0(v2f a) {
    return __builtin_elementwise_max(a, (v2f){0.0f, 0.0f});
}
__device__ __forceinline__ v2f v2_splat(float x) { return (v2f){x, x}; }

__device__ __forceinline__ float fast_rcp(float x) { return __builtin_amdgcn_rcpf(x); }

// ---------------- DPP cross-lane primitives (no LDS, ~2cyc) ----------------
#define DPP_ROW_SHR(n)  (0x110 | (n))
#define DPP_WF_SL1      0x130   /* lane i <- lane i+1 (shfl_down 1) */
#define DPP_WF_SR1      0x138   /* lane i <- lane i-1 (shfl_up 1)   */
#define DPP_ROW_BCAST15 0x142
#define DPP_ROW_BCAST31 0x143

template <int CTRL, int RM = 0xf, int BM = 0xf, bool BC = false>
__device__ __forceinline__ float fdpp(float old_, float src) {
    return __int_as_float(__builtin_amdgcn_update_dpp(
        __float_as_int(old_), __float_as_int(src), CTRL, RM, BM, BC));
}

__device__ __forceinline__ float lane63_bcast(float x) {
    return __int_as_float(__builtin_amdgcn_readlane(__float_as_int(x), 63));
}

// uniform broadcast of lane `l`'s value through an SGPR (VALU, no LDS traffic)
__device__ __forceinline__ float rdlane(float x, int l) {
    return __int_as_float(__builtin_amdgcn_readlane(__float_as_int(x), l));
}

// inclusive scan-add across 64 lanes (canonical gfx9 DPP sequence)
__device__ __forceinline__ float scan_add_dpp(float x) {
    x += fdpp<DPP_ROW_SHR(1)>(0.0f, x);
    x += fdpp<DPP_ROW_SHR(2)>(0.0f, x);
    x += fdpp<DPP_ROW_SHR(4)>(0.0f, x);
    x += fdpp<DPP_ROW_SHR(8)>(0.0f, x);
    x += fdpp<DPP_ROW_BCAST15, 0xa>(0.0f, x);
    x += fdpp<DPP_ROW_BCAST31, 0xc>(0.0f, x);
    return x;
}
// inclusive scan-mul across 64 lanes (identity = 1.0)
__device__ __forceinline__ float scan_mul_dpp(float x) {
    x *= fdpp<DPP_ROW_SHR(1)>(1.0f, x);
    x *= fdpp<DPP_ROW_SHR(2)>(1.0f, x);
    x *= fdpp<DPP_ROW_SHR(4)>(1.0f, x);
    x *= fdpp<DPP_ROW_SHR(8)>(1.0f, x);
    x *= fdpp<DPP_ROW_BCAST15, 0xa>(1.0f, x);
    x *= fdpp<DPP_ROW_BCAST31, 0xc>(1.0f, x);
    return x;
}
__device__ __forceinline__ float wave_sum_dpp(float x) {
    return lane63_bcast(scan_add_dpp(x));
}

__device__ __forceinline__ float softplus_f(float x) {
    return fmaxf(x, 0.0f) + __logf(1.0f + __expf(-fabsf(x)));
}
__device__ __forceinline__ float sigmoid_f(float x) {
    return fast_rcp(1.0f + __expf(-x));
}
__device__ __forceinline__ float clamp1(float x) {
    return fminf(fmaxf(x, -1.0f), 1.0f);
}

// count of a[j] < x over j in [0,64)
__device__ __forceinline__ int count_lt64(const float* a, float x) {
    int lo = 0, hi = 64;
    while (lo < hi) { int mid = (lo + hi) >> 1; if (a[mid] < x) lo = mid + 1; else hi = mid; }
    return lo;
}
// count of a[j] <= x over j in [0,64)
__device__ __forceinline__ int count_le64(const float* a, float x) {
    int lo = 0, hi = 64;
    while (lo < hi) { int mid = (lo + hi) >> 1; if (a[mid] <= x) lo = mid + 1; else hi = mid; }
    return lo;
}

__global__ __launch_bounds__(WAVES_PER_BLOCK * 64)
void nerf_render_kernel(const float* __restrict__ rays_o,
                        const float* __restrict__ rays_d,
                        const float* __restrict__ W1,      // [3,64]
                        const float* __restrict__ b1,      // [64]
                        const float* __restrict__ w_sigma, // [64,1]
                        const float* __restrict__ b_sigma, // [1]
                        const float* __restrict__ W_rgb,   // [64,3]
                        const float* __restrict__ b_rgb,   // [3]
                        float* __restrict__ out)           // [N,3]
{
    const int tid  = threadIdx.x;
    const int lane = tid & 63;
    const int wv   = tid >> 6;
    // readfirstlane: ray is wave-uniform; lets the compiler emit s_loads for
    // the 6 per-ray floats instead of per-lane vector loads.
    const int ray  = __builtin_amdgcn_readfirstlane(blockIdx.x * WAVES_PER_BLOCK + wv);

    // All LDS is wave-private ([wv] indexed). Intra-wave DS ops are
    // program-ordered, so NO __syncthreads() is needed anywhere in this
    // kernel — waves in a block run fully decoupled.
    // (c,m) in 16B granules: [4t..4t+3] = {c_{2t}, c_{2t+1}, m_{2t}, m_{2t+1}}
    __shared__ __align__(16) float s_cm  [WAVES_PER_BLOCK][128];
    __shared__ __align__(16) float s_zmid[WAVES_PER_BLOCK][64];
    __shared__ __align__(16) float s_cdf [WAVES_PER_BLOCK][64];
    __shared__ __align__(16) float s_zall[WAVES_PER_BLOCK][128];

    // ---- ray load + normalize ----
    float ox = rays_o[ray * 3 + 0], oy = rays_o[ray * 3 + 1], oz = rays_o[ray * 3 + 2];
    float dx = rays_d[ray * 3 + 0], dy = rays_d[ray * 3 + 1], dz = rays_d[ray * 3 + 2];
    {
        float inv = __builtin_amdgcn_rsqf(dx * dx + dy * dy + dz * dz);
        dx *= inv; dy *= inv; dz *= inv;
    }

    // ---- near/far vs [-1,1]^3 ----
    float rx = fast_rcp(dx + 1e-15f);
    float ry = fast_rcp(dy + 1e-15f);
    float rz = fast_rcp(dz + 1e-15f);
    float t0x = (-1.0f - ox) * rx, t1x = (1.0f - ox) * rx;
    float t0y = (-1.0f - oy) * ry, t1y = (1.0f - oy) * ry;
    float t0z = (-1.0f - oz) * rz, t1z = (1.0f - oz) * rz;
    float nearv = fmaxf(fmaxf(fminf(t0x, t1x), fminf(t0y, t1y)), fminf(t0z, t1z));
    float farv  = fminf(fminf(fmaxf(t0x, t1x), fmaxf(t0y, t1y)), fmaxf(t0z, t1z));
    const bool miss = (farv < nearv);
    if (miss) { nearv = 1e9f; farv = 1e9f; }
    nearv = fmaxf(nearv, 0.05f);
    const float sample_dist = (farv - nearv) * (1.0f / 64.0f);

    const float bs0 = b_sigma[0];
    const float br0 = b_rgb[0], br1 = b_rgb[1], br2 = b_rgb[2];

    // ---- per-ray affine layer-1: a_j(z) = c_j + m_j*z (clip is a no-op for
    // in-cube samples; miss rays use m=0, c at clamped corner).
    // Lane j OWNS unit j's (c_j, m_j) in registers; LDS copy only for the
    // fine loop's b128 granule reads.
    float cj, mj;
    {
        float w1x = W1[lane], w1y = W1[64 + lane], w1z = W1[128 + lane];
        float eox = ox, eoy = oy, eoz = oz, msc = 1.0f;
        if (miss) {
            eox = clamp1(fmaf(dx, 1e9f, ox));
            eoy = clamp1(fmaf(dy, 1e9f, oy));
            eoz = clamp1(fmaf(dz, 1e9f, oz));
            msc = 0.0f;
        }
        cj = fmaf(eox, w1x, fmaf(eoy, w1y, fmaf(eoz, w1z, b1[lane])));
        mj = msc * fmaf(dx, w1x, fmaf(dy, w1y, dz * w1z));
        int g = (lane >> 1) * 4 + (lane & 1);
        s_cm[wv][g]     = cj;
        s_cm[wv][g + 2] = mj;
        // intra-wave RAW on own slice: DS ops are program-ordered per wave.
    }

    // ---- coarse samples ----
    float z = nearv + (farv - nearv) * ((float)lane * (1.0f / 63.0f));

    // ---- coarse MLP (sigma only): h = relu(m*z + c).
    // Broadcast (c,m) via v_readlane (VALU/SGPR path) instead of uniform
    // ds_read_b128 — halves this kernel's pressure on the per-CU LDS pipe.
    const v2f* ws2 = (const v2f*)w_sigma;
    v2f z2 = v2_splat(z);
    v2f acc = (v2f){bs0, 0.0f};
#pragma unroll
    for (int t = 0; t < 32; ++t) {
        v2f cc = (v2f){rdlane(cj, 2 * t), rdlane(cj, 2 * t + 1)};
        v2f mm = (v2f){rdlane(mj, 2 * t), rdlane(mj, 2 * t + 1)};
        v2f h = v2_max0(v2_fma(mm, z2, cc));
        acc = v2_fma(h, ws2[t], acc);
    }
    float sigma = softplus_f(acc.x + acc.y);

    // ---- coarse alpha compositing -> weights ----
    float z_next = fdpp<DPP_WF_SL1>(0.0f, z);
    float delta  = (lane < 63) ? (z_next - z) : sample_dist;
    float alpha  = 1.0f - __expf(-delta * sigma);
    float v      = 1.0f - alpha + 1e-15f;
    float incl   = scan_mul_dpp(v);
    float trans  = fdpp<DPP_WF_SR1>(1.0f, incl);   // lane0 -> 1.0
    float w = alpha * trans;

    // ---- sample_pdf: unnormalized scan, total from lane63 of same scan ----
    float wgt = (lane >= 1 && lane <= 62) ? (w + 1e-5f) : 0.0f;
    float cumw = scan_add_dpp(wgt);
    float total = lane63_bcast(cumw);
    float cdf_incl = cumw * fast_rcp(total);

    float zmid = 0.5f * (z + z_next);
    s_zmid[wv][lane] = (lane < 63) ? zmid : 0.0f;
    s_cdf [wv][lane] = (lane < 63) ? cdf_incl : 2.0f;  // sentinel

    float u = 0.0078125f + (float)lane * 0.015625f;
    int ind = count_le64(s_cdf[wv], u);
    int below = ind - 1;
    int above = (ind < 62) ? ind : 62;
    float cb = s_cdf[wv][below], ca = s_cdf[wv][above];
    float bb = s_zmid[wv][below], ba = s_zmid[wv][above];
    float denom = ca - cb;
    if (denom < 1e-5f) denom = 1.0f;
    float t = (u - cb) * fast_rcp(denom);
    float nz = fmaf(t, ba - bb, bb);

    // ---- rank-merge concat(z, new_z) -> 128 sorted ----
    // WAR on s_zmid/s_cdf handled by in-order per-wave DS pipeline.
    s_zmid[wv][lane] = z;
    s_cdf [wv][lane] = nz;
    int pa = lane + count_lt64(s_cdf [wv], z);
    int pb = lane + count_le64(s_zmid[wv], nz);
    s_zall[wv][pa] = z;
    s_zall[wv][pb] = nz;

    v2f za = *(const v2f*)&s_zall[wv][2 * lane];
    float za0 = za.x;
    float za1 = za.y;

    // ---- fine MLP at both points, packed over sample pair, b128 granules ----
    v2f zz = (v2f){za0, za1};
    v2f s2 = v2_splat(bs0);
    v2f r2 = v2_splat(br0), g2 = v2_splat(br1), bch2 = v2_splat(br2);
#pragma unroll 8
    for (int t = 0; t < 32; ++t) {
        v4f g = *(const v4f*)&s_cm[wv][4 * t];
        int j0 = 2 * t, j1 = 2 * t + 1;
        v2f h0 = v2_max0(v2_fma(v2_splat(g.z), zz, v2_splat(g.x)));
        s2   = v2_fma(h0, v2_splat(w_sigma[j0]),       s2);
        r2   = v2_fma(h0, v2_splat(W_rgb[3 * j0 + 0]), r2);
        g2   = v2_fma(h0, v2_splat(W_rgb[3 * j0 + 1]), g2);
        bch2 = v2_fma(h0, v2_splat(W_rgb[3 * j0 + 2]), bch2);
        v2f h1 = v2_max0(v2_fma(v2_splat(g.w), zz, v2_splat(g.y)));
        s2   = v2_fma(h1, v2_splat(w_sigma[j1]),       s2);
        r2   = v2_fma(h1, v2_splat(W_rgb[3 * j1 + 0]), r2);
        g2   = v2_fma(h1, v2_splat(W_rgb[3 * j1 + 1]), g2);
        bch2 = v2_fma(h1, v2_splat(W_rgb[3 * j1 + 2]), bch2);
    }
    float sg0 = softplus_f(s2.x), sg1 = softplus_f(s2.y);
    float r0 = sigmoid_f(r2.x),   r1 = sigmoid_f(r2.y);
    float g0 = sigmoid_f(g2.x),   g1 = sigmoid_f(g2.y);
    float bl0 = sigmoid_f(bch2.x), bl1 = sigmoid_f(bch2.y);

    // ---- fine compositing over 128 samples (2/lane) ----
    float zn0 = fdpp<DPP_WF_SL1>(0.0f, za0);
    float d0 = za1 - za0;
    float d1 = (lane < 63) ? (zn0 - za1) : sample_dist;
    float a0 = 1.0f - __expf(-d0 * sg0);
    float a1 = 1.0f - __expf(-d1 * sg1);
    float v0 = 1.0f - a0 + 1e-15f;
    float v1 = 1.0f - a1 + 1e-15f;
    float local = v0 * v1;
    float incl2 = scan_mul_dpp(local);
    float eprod = fdpp<DPP_WF_SR1>(1.0f, incl2);   // lane0 -> 1.0
    float w0 = a0 * eprod;
    float w1 = a1 * (eprod * v0);

    float wsum = wave_sum_dpp(w0 + w1);
    float rs   = wave_sum_dpp(fmaf(w0, r0,  w1 * r1));
    float gs   = wave_sum_dpp(fmaf(w0, g0,  w1 * g1));
    float bs   = wave_sum_dpp(fmaf(w0, bl0, w1 * bl1));

    if (lane == 0) {
        float bg = 1.0f - wsum;
        out[ray * 3 + 0] = rs + bg;
        out[ray * 3 + 1] = gs + bg;
        out[ray * 3 + 2] = bs + bg;
    }
}

extern "C" void kernel_launch(void* const* d_in, const int* in_sizes, int n_in,
                              void* d_out, int out_size, void* d_ws, size_t ws_size,
                              hipStream_t stream) {
    const float* rays_o  = (const float*)d_in[0];
    const float* rays_d  = (const float*)d_in[1];
    const float* W1      = (const float*)d_in[2];
    const float* b1      = (const float*)d_in[3];
    const float* w_sigma = (const float*)d_in[4];
    const float* b_sigma = (const float*)d_in[5];
    const float* W_rgb   = (const float*)d_in[6];
    const float* b_rgb   = (const float*)d_in[7];
    float* out = (float*)d_out;

    const int n_rays = in_sizes[0] / 3;
    dim3 grid((n_rays + WAVES_PER_BLOCK - 1) / WAVES_PER_BLOCK);
    dim3 block(WAVES_PER_BLOCK * 64);
    hipLaunchKernelGGL(nerf_render_kernel, grid, block, 0, stream,
                       rays_o, rays_d, W1, b1, w_sigma, b_sigma, W_rgb, b_rgb, out);
}

// Round 3
// 95.991 us; speedup vs baseline: 1.0605x; 1.0605x over previous
//
#include <hip/hip_runtime.h>
#include <math.h>

#define WAVES_PER_BLOCK 4

typedef float v2f __attribute__((ext_vector_type(2)));
typedef float v4f __attribute__((ext_vector_type(4)));

__device__ __forceinline__ v2f v2_fma(v2f a, v2f b, v2f c) {
    return __builtin_elementwise_fma(a, b, c);
}
__device__ __forceinline__ v2f v2_max0(v2f a) {
    return __builtin_elementwise_max(a, (v2f){0.0f, 0.0f});
}
__device__ __forceinline__ v2f v2_splat(float x) { return (v2f){x, x}; }

__device__ __forceinline__ float fast_rcp(float x) { return __builtin_amdgcn_rcpf(x); }

// ---------------- DPP cross-lane primitives (no LDS, ~2cyc) ----------------
#define DPP_ROW_SHR(n)  (0x110 | (n))
#define DPP_WF_SL1      0x130   /* lane i <- lane i+1 (shfl_down 1) */
#define DPP_WF_SR1      0x138   /* lane i <- lane i-1 (shfl_up 1)   */
#define DPP_ROW_BCAST15 0x142
#define DPP_ROW_BCAST31 0x143

template <int CTRL, int RM = 0xf, int BM = 0xf, bool BC = false>
__device__ __forceinline__ float fdpp(float old_, float src) {
    return __int_as_float(__builtin_amdgcn_update_dpp(
        __float_as_int(old_), __float_as_int(src), CTRL, RM, BM, BC));
}

__device__ __forceinline__ float lane63_bcast(float x) {
    return __int_as_float(__builtin_amdgcn_readlane(__float_as_int(x), 63));
}
// uniform broadcast of lane `l` (compile-time) through an SGPR — VALU only
__device__ __forceinline__ float rdlane(float x, int l) {
    return __int_as_float(__builtin_amdgcn_readlane(__float_as_int(x), l));
}

// inclusive scan-add across 64 lanes (canonical gfx9 DPP sequence)
__device__ __forceinline__ float scan_add_dpp(float x) {
    x += fdpp<DPP_ROW_SHR(1)>(0.0f, x);
    x += fdpp<DPP_ROW_SHR(2)>(0.0f, x);
    x += fdpp<DPP_ROW_SHR(4)>(0.0f, x);
    x += fdpp<DPP_ROW_SHR(8)>(0.0f, x);
    x += fdpp<DPP_ROW_BCAST15, 0xa>(0.0f, x);
    x += fdpp<DPP_ROW_BCAST31, 0xc>(0.0f, x);
    return x;
}
// inclusive scan-mul across 64 lanes (identity = 1.0)
__device__ __forceinline__ float scan_mul_dpp(float x) {
    x *= fdpp<DPP_ROW_SHR(1)>(1.0f, x);
    x *= fdpp<DPP_ROW_SHR(2)>(1.0f, x);
    x *= fdpp<DPP_ROW_SHR(4)>(1.0f, x);
    x *= fdpp<DPP_ROW_SHR(8)>(1.0f, x);
    x *= fdpp<DPP_ROW_BCAST15, 0xa>(1.0f, x);
    x *= fdpp<DPP_ROW_BCAST31, 0xc>(1.0f, x);
    return x;
}
__device__ __forceinline__ float wave_sum_dpp(float x) {
    return lane63_bcast(scan_add_dpp(x));
}

__device__ __forceinline__ float softplus_f(float x) {
    return fmaxf(x, 0.0f) + __logf(1.0f + __expf(-fabsf(x)));
}
__device__ __forceinline__ float sigmoid_f(float x) {
    return fast_rcp(1.0f + __expf(-x));
}
__device__ __forceinline__ float clamp1(float x) {
    return fminf(fmaxf(x, -1.0f), 1.0f);
}

// ---- 2-level rank over a sorted 64-entry wave-private LDS array ----------
// `own` = this lane's element of the array (array[lane] == own), so the 8
// pivots a[8t+7] come from v_readlane (wave-uniform SGPRs, zero memory
// latency).  Level 2 fetches the selected octant with two INDEPENDENT
// ds_read_b128 — one LDS round-trip instead of six dependent b32 reads.
// Exact same count semantics as a binary search.
template <bool LE>
__device__ __forceinline__ int rank2(const float* a, float own, float x) {
    int o = 0;
#pragma unroll
    for (int t = 0; t < 8; ++t) {
        float p = rdlane(own, 8 * t + 7);
        o += (int)(LE ? (p <= x) : (p < x));
    }
    o = (o < 7) ? o : 7;            // x beyond a[63]: count within last octant
    const v4f q0 = *(const v4f*)&a[8 * o];
    const v4f q1 = *(const v4f*)&a[8 * o + 4];
    int cnt = 0;
    cnt += (int)(LE ? (q0.x <= x) : (q0.x < x));
    cnt += (int)(LE ? (q0.y <= x) : (q0.y < x));
    cnt += (int)(LE ? (q0.z <= x) : (q0.z < x));
    cnt += (int)(LE ? (q0.w <= x) : (q0.w < x));
    cnt += (int)(LE ? (q1.x <= x) : (q1.x < x));
    cnt += (int)(LE ? (q1.y <= x) : (q1.y < x));
    cnt += (int)(LE ? (q1.z <= x) : (q1.z < x));
    cnt += (int)(LE ? (q1.w <= x) : (q1.w < x));
    return 8 * o + cnt;
}

__global__ __launch_bounds__(WAVES_PER_BLOCK * 64)
void nerf_render_kernel(const float* __restrict__ rays_o,
                        const float* __restrict__ rays_d,
                        const float* __restrict__ W1,      // [3,64]
                        const float* __restrict__ b1,      // [64]
                        const float* __restrict__ w_sigma, // [64,1]
                        const float* __restrict__ b_sigma, // [1]
                        const float* __restrict__ W_rgb,   // [64,3]
                        const float* __restrict__ b_rgb,   // [3]
                        float* __restrict__ out)           // [N,3]
{
    const int tid  = threadIdx.x;
    const int lane = tid & 63;
    const int wv   = tid >> 6;
    // ray index is wave-uniform -> scalar loads for the 6 per-ray floats
    const int ray  = __builtin_amdgcn_readfirstlane(blockIdx.x * WAVES_PER_BLOCK + wv);

    // All LDS is wave-private ([wv] indexed); intra-wave DS ops are
    // program-ordered, so no __syncthreads() anywhere (validated: passes).
    // (c,m) in 16B granules: [4t..4t+3] = {c_{2t}, c_{2t+1}, m_{2t}, m_{2t+1}}
    __shared__ __align__(16) float s_cm  [WAVES_PER_BLOCK][128];
    __shared__ __align__(16) float s_zmid[WAVES_PER_BLOCK][64];
    __shared__ __align__(16) float s_cdf [WAVES_PER_BLOCK][64];
    __shared__ __align__(16) float s_zall[WAVES_PER_BLOCK][128];

    // ---- ray load + normalize ----
    float ox = rays_o[ray * 3 + 0], oy = rays_o[ray * 3 + 1], oz = rays_o[ray * 3 + 2];
    float dx = rays_d[ray * 3 + 0], dy = rays_d[ray * 3 + 1], dz = rays_d[ray * 3 + 2];
    {
        float inv = __builtin_amdgcn_rsqf(dx * dx + dy * dy + dz * dz);
        dx *= inv; dy *= inv; dz *= inv;
    }

    // ---- near/far vs [-1,1]^3 ----
    float rx = fast_rcp(dx + 1e-15f);
    float ry = fast_rcp(dy + 1e-15f);
    float rz = fast_rcp(dz + 1e-15f);
    float t0x = (-1.0f - ox) * rx, t1x = (1.0f - ox) * rx;
    float t0y = (-1.0f - oy) * ry, t1y = (1.0f - oy) * ry;
    float t0z = (-1.0f - oz) * rz, t1z = (1.0f - oz) * rz;
    float nearv = fmaxf(fmaxf(fminf(t0x, t1x), fminf(t0y, t1y)), fminf(t0z, t1z));
    float farv  = fminf(fminf(fmaxf(t0x, t1x), fmaxf(t0y, t1y)), fmaxf(t0z, t1z));
    const bool miss = (farv < nearv);
    if (miss) { nearv = 1e9f; farv = 1e9f; }
    nearv = fmaxf(nearv, 0.05f);
    const float sample_dist = (farv - nearv) * (1.0f / 64.0f);

    const float bs0 = b_sigma[0];
    const float br0 = b_rgb[0], br1 = b_rgb[1], br2 = b_rgb[2];

    // ---- per-ray affine layer-1: a_j(z) = c_j + m_j*z ----
    {
        float w1x = W1[lane], w1y = W1[64 + lane], w1z = W1[128 + lane];
        float eox = ox, eoy = oy, eoz = oz, msc = 1.0f;
        if (miss) {
            eox = clamp1(fmaf(dx, 1e9f, ox));
            eoy = clamp1(fmaf(dy, 1e9f, oy));
            eoz = clamp1(fmaf(dz, 1e9f, oz));
            msc = 0.0f;
        }
        float cj = fmaf(eox, w1x, fmaf(eoy, w1y, fmaf(eoz, w1z, b1[lane])));
        float mj = msc * fmaf(dx, w1x, fmaf(dy, w1y, dz * w1z));
        int g = (lane >> 1) * 4 + (lane & 1);
        s_cm[wv][g]     = cj;
        s_cm[wv][g + 2] = mj;
    }

    // ---- coarse samples ----
    float z = nearv + (farv - nearv) * ((float)lane * (1.0f / 63.0f));

    // ---- coarse MLP (sigma only): h = relu(m*z + c), uniform b128 LDS
    // broadcasts (idle pipe; latency hidden at 8 waves/SIMD — readlane
    // variant measured SLOWER, VALU is the binding pipe) ----
    const v2f* ws2 = (const v2f*)w_sigma;
    v2f z2 = v2_splat(z);
    v2f acc = (v2f){bs0, 0.0f};
#pragma unroll 8
    for (int t = 0; t < 32; ++t) {
        v4f g = *(const v4f*)&s_cm[wv][4 * t];
        v2f h = v2_max0(v2_fma((v2f){g.z, g.w}, z2, (v2f){g.x, g.y}));
        acc = v2_fma(h, ws2[t], acc);
    }
    float sigma = softplus_f(acc.x + acc.y);

    // ---- coarse alpha compositing -> weights ----
    float z_next = fdpp<DPP_WF_SL1>(0.0f, z);
    float delta  = (lane < 63) ? (z_next - z) : sample_dist;
    float alpha  = 1.0f - __expf(-delta * sigma);
    float v      = 1.0f - alpha + 1e-15f;
    float incl   = scan_mul_dpp(v);
    float trans  = fdpp<DPP_WF_SR1>(1.0f, incl);   // lane0 -> 1.0
    float w = alpha * trans;

    // ---- sample_pdf: unnormalized scan, total from lane63 of same scan ----
    float wgt = (lane >= 1 && lane <= 62) ? (w + 1e-5f) : 0.0f;
    float cumw = scan_add_dpp(wgt);
    float total = lane63_bcast(cumw);
    float cdf_incl = cumw * fast_rcp(total);

    float zmid = 0.5f * (z + z_next);
    float cdfv = (lane < 63) ? cdf_incl : 2.0f;    // array value incl sentinel
    s_zmid[wv][lane] = (lane < 63) ? zmid : 0.0f;
    s_cdf [wv][lane] = cdfv;

    float u = 0.0078125f + (float)lane * 0.015625f;
    int ind = rank2<true>(s_cdf[wv], cdfv, u);     // == count_le64(s_cdf, u)
    int below = ind - 1;
    int above = (ind < 62) ? ind : 62;
    float cb = s_cdf[wv][below], ca = s_cdf[wv][above];
    float bb = s_zmid[wv][below], ba = s_zmid[wv][above];
    float denom = ca - cb;
    if (denom < 1e-5f) denom = 1.0f;
    float t = (u - cb) * fast_rcp(denom);
    float nz = fmaf(t, ba - bb, bb);

    // ---- rank-merge concat(z, new_z) -> 128 sorted ----
    s_zmid[wv][lane] = z;      // array of z's   (z_lane == own)
    s_cdf [wv][lane] = nz;     // array of nz's  (nz     == own)
    int pa = lane + rank2<false>(s_cdf [wv], nz, z);  // count_lt64(nz_arr, z)
    int pb = lane + rank2<true >(s_zmid[wv], z,  nz); // count_le64(z_arr, nz)
    s_zall[wv][pa] = z;
    s_zall[wv][pb] = nz;

    v2f za = *(const v2f*)&s_zall[wv][2 * lane];
    float za0 = za.x;
    float za1 = za.y;

    // ---- fine MLP at both points, packed over sample pair, b128 granules ----
    v2f zz = (v2f){za0, za1};
    v2f s2 = v2_splat(bs0);
    v2f r2 = v2_splat(br0), g2 = v2_splat(br1), bch2 = v2_splat(br2);
#pragma unroll 8
    for (int t = 0; t < 32; ++t) {
        v4f g = *(const v4f*)&s_cm[wv][4 * t];
        int j0 = 2 * t, j1 = 2 * t + 1;
        v2f h0 = v2_max0(v2_fma(v2_splat(g.z), zz, v2_splat(g.x)));
        s2   = v2_fma(h0, v2_splat(w_sigma[j0]),       s2);
        r2   = v2_fma(h0, v2_splat(W_rgb[3 * j0 + 0]), r2);
        g2   = v2_fma(h0, v2_splat(W_rgb[3 * j0 + 1]), g2);
        bch2 = v2_fma(h0, v2_splat(W_rgb[3 * j0 + 2]), bch2);
        v2f h1 = v2_max0(v2_fma(v2_splat(g.w), zz, v2_splat(g.y)));
        s2   = v2_fma(h1, v2_splat(w_sigma[j1]),       s2);
        r2   = v2_fma(h1, v2_splat(W_rgb[3 * j1 + 0]), r2);
        g2   = v2_fma(h1, v2_splat(W_rgb[3 * j1 + 1]), g2);
        bch2 = v2_fma(h1, v2_splat(W_rgb[3 * j1 + 2]), bch2);
    }
    float sg0 = softplus_f(s2.x), sg1 = softplus_f(s2.y);
    float r0 = sigmoid_f(r2.x),   r1 = sigmoid_f(r2.y);
    float g0 = sigmoid_f(g2.x),   g1 = sigmoid_f(g2.y);
    float bl0 = sigmoid_f(bch2.x), bl1 = sigmoid_f(bch2.y);

    // ---- fine compositing over 128 samples (2/lane) ----
    float zn0 = fdpp<DPP_WF_SL1>(0.0f, za0);
    float d0 = za1 - za0;
    float d1 = (lane < 63) ? (zn0 - za1) : sample_dist;
    float a0 = 1.0f - __expf(-d0 * sg0);
    float a1 = 1.0f - __expf(-d1 * sg1);
    float v0 = 1.0f - a0 + 1e-15f;
    float v1 = 1.0f - a1 + 1e-15f;
    float local = v0 * v1;
    float incl2 = scan_mul_dpp(local);
    float eprod = fdpp<DPP_WF_SR1>(1.0f, incl2);   // lane0 -> 1.0
    float w0 = a0 * eprod;
    float w1 = a1 * (eprod * v0);

    float wsum = wave_sum_dpp(w0 + w1);
    float rs   = wave_sum_dpp(fmaf(w0, r0,  w1 * r1));
    float gs   = wave_sum_dpp(fmaf(w0, g0,  w1 * g1));
    float bs   = wave_sum_dpp(fmaf(w0, bl0, w1 * bl1));

    if (lane == 0) {
        float bg = 1.0f - wsum;
        out[ray * 3 + 0] = rs + bg;
        out[ray * 3 + 1] = gs + bg;
        out[ray * 3 + 2] = bs + bg;
    }
}

extern "C" void kernel_launch(void* const* d_in, const int* in_sizes, int n_in,
                              void* d_out, int out_size, void* d_ws, size_t ws_size,
                              hipStream_t stream) {
    const float* rays_o  = (const float*)d_in[0];
    const float* rays_d  = (const float*)d_in[1];
    const float* W1      = (const float*)d_in[2];
    const float* b1      = (const float*)d_in[3];
    const float* w_sigma = (const float*)d_in[4];
    const float* b_sigma = (const float*)d_in[5];
    const float* W_rgb   = (const float*)d_in[6];
    const float* b_rgb   = (const float*)d_in[7];
    float* out = (float*)d_out;

    const int n_rays = in_sizes[0] / 3;
    dim3 grid((n_rays + WAVES_PER_BLOCK - 1) / WAVES_PER_BLOCK);
    dim3 block(WAVES_PER_BLOCK * 64);
    hipLaunchKernelGGL(nerf_render_kernel, grid, block, 0, stream,
                       rays_o, rays_d, W1, b1, w_sigma, b_sigma, W_rgb, b_rgb, out);
}